// Round 7
// baseline (348.253 us; speedup 1.0000x reference)
//
#include <hip/hip_runtime.h>
#include <float.h>

#define T_TOTAL 32768
#define KC      8192
#define DIM     256

#define LOSS_IDX  ((size_t)T_TOTAL * DIM)      // 8388608
#define USAGE_IDX (LOSS_IDX + 1)

typedef short s16x8 __attribute__((ext_vector_type(8)));
typedef float f32x4 __attribute__((ext_vector_type(4)));

// ws layout (bytes):
#define WS_W2    0                 // f32[8192]
#define WS_FLAGS 32768             // i32[8192]
#define WS_CBF   65536             // u16[8192*256] = 4 MB

__device__ __forceinline__ unsigned short f2bf(float f) {
    unsigned int u = __float_as_uint(f);
    u += 0x7FFFu + ((u >> 16) & 1u);   // RTNE
    return (unsigned short)(u >> 16);
}

// ---------------------------------------------------------------------------
// prep: cb->bf16 + exact fp32 w2; flags zero (blocks 0..31); scalars (block 0)
__global__ __launch_bounds__(256) void vq_prep(const float* __restrict__ cb,
                                               unsigned short* __restrict__ cbb,
                                               float* __restrict__ w2,
                                               int* __restrict__ flags,
                                               float* __restrict__ out) {
    const int blk = blockIdx.x, tid = threadIdx.x;
    size_t i = (size_t)blk * 2048 + (size_t)tid * 8;
    float4 a = *(const float4*)(cb + i);
    float4 b = *(const float4*)(cb + i + 4);
    uint4 o;
    o.x = (unsigned)f2bf(a.x) | ((unsigned)f2bf(a.y) << 16);
    o.y = (unsigned)f2bf(a.z) | ((unsigned)f2bf(a.w) << 16);
    o.z = (unsigned)f2bf(b.x) | ((unsigned)f2bf(b.y) << 16);
    o.w = (unsigned)f2bf(b.z) | ((unsigned)f2bf(b.w) << 16);
    *(uint4*)(cbb + i) = o;
    float s = a.x * a.x + a.y * a.y + a.z * a.z + a.w * a.w
            + b.x * b.x + b.y * b.y + b.z * b.z + b.w * b.w;
    #pragma unroll
    for (int m = 1; m <= 16; m <<= 1) s += __shfl_xor(s, m);
    if ((tid & 31) == 0) w2[blk * 8 + (tid >> 5)] = s;
    if (blk < 32) flags[blk * 256 + tid] = 0;
    if (blk == 0 && tid == 0) { out[LOSS_IDX] = 0.0f; out[USAGE_IDX] = 0.0f; }
}

// ---------------------------------------------------------------------------
// main: block = 128 tokens x all 8192 codes, grid 256 (1 block/CU), 8 waves.
// wave w: wr=w>>2 token half (64 tokens, 4 A-frags held in regs/AGPRs),
// wc=w&3 code quarter (32 codes per 128-chunk).
// NO LDS in the K-loop: B fragments are loaded straight into a register
// double-buffer with global_load_dwordx4 (per-lane 16B, 16 rows x 64 B per
// instruction, L1/L2-resident). Compiler-tracked register deps give
// fine-grained vmcnt(N) waits (never 0) -> loads of window n+1 stay in
// flight across window n's MFMAs. Waves run barrier-free and desynced.
__global__ __launch_bounds__(512, 2) void vq_main(const unsigned short* __restrict__ cbb,
                                                  const float* __restrict__ w2g,
                                                  const float* __restrict__ z_e,
                                                  const float* __restrict__ cb,
                                                  float* __restrict__ out,
                                                  int* __restrict__ flags) {
    __shared__ unsigned long long smin[128];
    __shared__ float wls[8];

    const int tid  = threadIdx.x;
    const int lane = tid & 63;
    const int w    = tid >> 6;        // 0..7
    const int wr   = w >> 2;          // token half
    const int wc   = w & 3;           // code quarter
    const int quad = lane >> 4;
    const int l15  = lane & 15;
    const int t0   = blockIdx.x * 128;

    if (tid < 128) smin[tid] = ~0ULL;
    __syncthreads();                  // smin published before any wave's epilogue

    // per-lane B base: code row (wc*32 + l15), k-offset quad*8
    const unsigned short* pB = cbb + (size_t)(wc * 32 + l15) * DIM + quad * 8;

    // window WIN (0..127): chunk c = WIN>>1 (codes c*128 + wc*32 + j*16),
    // k-half kw = WIN&1 (k = kw*128 + kk*32). 8 fragment loads per window.
    #define LOADB(BUF, WIN)                                                             \
        {                                                                               \
            size_t _off = (size_t)((WIN) >> 1) * 128 * DIM + ((WIN) & 1) * 128;         \
            _Pragma("unroll")                                                           \
            for (int kk = 0; kk < 4; ++kk)                                              \
                _Pragma("unroll")                                                       \
                for (int j = 0; j < 2; ++j)                                             \
                    (BUF)[kk * 2 + j] = *(const s16x8*)(pB + _off + (size_t)(j * 16) * DIM + kk * 32); \
        }

    // ---- A prologue: fp32 z_e -> bf16 fragments (held in regs/AGPRs) ----
    s16x8 bf[2][8];
    LOADB(bf[0], 0);   // window-0 loads in flight during A build
    s16x8 af[4][8];
    #pragma unroll
    for (int i = 0; i < 4; ++i) {
        #pragma unroll
        for (int ks = 0; ks < 8; ++ks) {
            const float* p = z_e + (size_t)(t0 + wr * 64 + i * 16 + l15) * DIM + ks * 32 + quad * 8;
            float4 a = *(const float4*)p;
            float4 b = *(const float4*)(p + 4);
            s16x8 v;
            v[0] = (short)f2bf(a.x); v[1] = (short)f2bf(a.y);
            v[2] = (short)f2bf(a.z); v[3] = (short)f2bf(a.w);
            v[4] = (short)f2bf(b.x); v[5] = (short)f2bf(b.y);
            v[6] = (short)f2bf(b.z); v[7] = (short)f2bf(b.w);
            af[i][ks] = v;
        }
    }

    float best[4][4];
    int   bidx[4][4];
    #pragma unroll
    for (int i = 0; i < 4; ++i)
        #pragma unroll
        for (int r = 0; r < 4; ++r) { best[i][r] = FLT_MAX; bidx[i][r] = 0x7FFFFFFF; }

    for (int c = 0; c < 64; ++c) {
        f32x4 acc[4][2];
        #pragma unroll
        for (int i = 0; i < 4; ++i)
            #pragma unroll
            for (int j = 0; j < 2; ++j) acc[i][j] = (f32x4){0.f, 0.f, 0.f, 0.f};

        #pragma unroll
        for (int kw = 0; kw < 2; ++kw) {
            const int win = c * 2 + kw;
            // prefetch next window into the other register buffer
            if (win < 127) LOADB(bf[(win + 1) & 1], win + 1);
            // 32 MFMAs on current window (first use waits vmcnt for window-win
            // loads only; the 8 just-issued stay outstanding)
            s16x8* cur = bf[win & 1];
            #pragma unroll
            for (int kk = 0; kk < 4; ++kk)
                #pragma unroll
                for (int i = 0; i < 4; ++i)
                    #pragma unroll
                    for (int j = 0; j < 2; ++j)
                        acc[i][j] = __builtin_amdgcn_mfma_f32_16x16x32_bf16(af[i][kw * 4 + kk], cur[kk * 2 + j], acc[i][j], 0, 0, 0);
        }

        // fold chunk c into running argmin: score = w2[col] - 2*dot
        #pragma unroll
        for (int j = 0; j < 2; ++j) {
            int col = c * 128 + wc * 32 + j * 16 + l15;
            float w2v = w2g[col];
            #pragma unroll
            for (int i = 0; i < 4; ++i)
                #pragma unroll
                for (int r = 0; r < 4; ++r) {
                    float s = fmaf(-2.0f, acc[i][j][r], w2v);
                    if (s < best[i][r]) { best[i][r] = s; bidx[i][r] = col; }  // ascending col: < keeps lowest
                }
        }
    }

    // cross-lane argmin over the 16 cols held per token row, then merge quarters
    #pragma unroll
    for (int i = 0; i < 4; ++i)
        #pragma unroll
        for (int r = 0; r < 4; ++r) {
            float b = best[i][r]; int ix = bidx[i][r];
            #pragma unroll
            for (int m = 1; m < 16; m <<= 1) {
                float ob = __shfl_xor(b, m);
                int   oi = __shfl_xor(ix, m);
                if (ob < b || (ob == b && oi < ix)) { b = ob; ix = oi; }
            }
            if (l15 == 0) {
                unsigned int fb = __float_as_uint(b);
                fb = (fb & 0x80000000u) ? ~fb : (fb | 0x80000000u);   // monotonic key
                unsigned long long key = ((unsigned long long)fb << 32) | (unsigned int)ix;
                atomicMin(&smin[wr * 64 + i * 16 + quad * 4 + r], key);
            }
        }
    __syncthreads();   // all waves' argmin merged before gather

    // fused gather + loss + flags: wave w -> tokens [w*16, w*16+16)
    float lsum = 0.0f;
    for (int t = w * 16; t < w * 16 + 16; ++t) {
        int tok = t0 + t;
        int k = (int)(unsigned int)(smin[t] & 0xFFFFFFFFull);
        if (lane == 0) flags[k] = 1;   // benign race
        float4 cv = *(const float4*)(cb + (size_t)k * DIM + lane * 4);
        float4 zv = *(const float4*)(z_e + (size_t)tok * DIM + lane * 4);
        float dx = zv.x - cv.x, dy = zv.y - cv.y, dz = zv.z - cv.z, dw = zv.w - cv.w;
        lsum += dx * dx + dy * dy + dz * dz + dw * dw;
        *(float4*)(out + (size_t)tok * DIM + lane * 4) = cv;
    }
    #pragma unroll
    for (int m = 32; m >= 1; m >>= 1) lsum += __shfl_xor(lsum, m);
    if (lane == 0) wls[w] = lsum;
    __syncthreads();
    if (tid == 0) {
        float bsum = 0.0f;
        #pragma unroll
        for (int q = 0; q < 8; ++q) bsum += wls[q];
        // loss = codebook + 0.25*commitment = 1.25 * mean(diff^2)
        atomicAdd(out + LOSS_IDX, bsum * (1.25f / (float)LOSS_IDX));
    }
}

// ---------------------------------------------------------------------------
__global__ __launch_bounds__(256) void vq_usage(const int* __restrict__ flags,
                                                float* __restrict__ out) {
    __shared__ int ws[4];
    int tid = threadIdx.x;
    int s = 0;
    for (int i = tid; i < KC; i += 256) s += flags[i];
    #pragma unroll
    for (int m = 32; m >= 1; m >>= 1) s += __shfl_xor(s, m);
    if ((tid & 63) == 0) ws[tid >> 6] = s;
    __syncthreads();
    if (tid == 0) out[USAGE_IDX] = (float)(ws[0] + ws[1] + ws[2] + ws[3]) / (float)KC;
}

// ---------------------------------------------------------------------------
extern "C" void kernel_launch(void* const* d_in, const int* in_sizes, int n_in,
                              void* d_out, int out_size, void* d_ws, size_t ws_size,
                              hipStream_t stream) {
    (void)in_sizes; (void)n_in; (void)out_size; (void)ws_size;
    const float* z_e = (const float*)d_in[0];
    const float* cb  = (const float*)d_in[1];
    float* out = (float*)d_out;

    char* ws = (char*)d_ws;
    float* w2    = (float*)(ws + WS_W2);
    int*   flags = (int*)(ws + WS_FLAGS);
    unsigned short* cbb = (unsigned short*)(ws + WS_CBF);

    vq_prep<<<KC / 8, 256, 0, stream>>>(cb, cbb, w2, flags, out);
    vq_main<<<T_TOTAL / 128, 512, 0, stream>>>(cbb, w2, z_e, cb, out, flags);
    vq_usage<<<1, 256, 0, stream>>>(flags, out);
}

// Round 8
// 245.695 us; speedup vs baseline: 1.4174x; 1.4174x over previous
//
#include <hip/hip_runtime.h>
#include <float.h>

#define T_TOTAL 32768
#define KC      8192
#define DIM     256

#define LOSS_IDX  ((size_t)T_TOTAL * DIM)      // 8388608
#define USAGE_IDX (LOSS_IDX + 1)

typedef short s16x8 __attribute__((ext_vector_type(8)));
typedef float f32x4 __attribute__((ext_vector_type(4)));

// ws layout (bytes):
#define WS_W2    0                 // f32[8192]
#define WS_FLAGS 32768             // i32[8192]
#define WS_CBF   65536             // u16[8192*256] = 4 MB

__device__ __forceinline__ unsigned short f2bf(float f) {
    unsigned int u = __float_as_uint(f);
    u += 0x7FFFu + ((u >> 16) & 1u);   // RTNE
    return (unsigned short)(u >> 16);
}

// ---------------------------------------------------------------------------
// prep: cb->bf16 + exact fp32 w2; flags zero (blocks 0..31); scalars (block 0)
__global__ __launch_bounds__(256) void vq_prep(const float* __restrict__ cb,
                                               unsigned short* __restrict__ cbb,
                                               float* __restrict__ w2,
                                               int* __restrict__ flags,
                                               float* __restrict__ out) {
    const int blk = blockIdx.x, tid = threadIdx.x;
    size_t i = (size_t)blk * 2048 + (size_t)tid * 8;
    float4 a = *(const float4*)(cb + i);
    float4 b = *(const float4*)(cb + i + 4);
    uint4 o;
    o.x = (unsigned)f2bf(a.x) | ((unsigned)f2bf(a.y) << 16);
    o.y = (unsigned)f2bf(a.z) | ((unsigned)f2bf(a.w) << 16);
    o.z = (unsigned)f2bf(b.x) | ((unsigned)f2bf(b.y) << 16);
    o.w = (unsigned)f2bf(b.z) | ((unsigned)f2bf(b.w) << 16);
    *(uint4*)(cbb + i) = o;
    float s = a.x * a.x + a.y * a.y + a.z * a.z + a.w * a.w
            + b.x * b.x + b.y * b.y + b.z * b.z + b.w * b.w;
    #pragma unroll
    for (int m = 1; m <= 16; m <<= 1) s += __shfl_xor(s, m);
    if ((tid & 31) == 0) w2[blk * 8 + (tid >> 5)] = s;
    if (blk < 32) flags[blk * 256 + tid] = 0;
    if (blk == 0 && tid == 0) { out[LOSS_IDX] = 0.0f; out[USAGE_IDX] = 0.0f; }
}

// ---------------------------------------------------------------------------
// main: block = 128 tokens x all 8192 codes, grid 256 (1 block/CU), 8 waves.
// wave w: wr=w>>2 token half (64 tokens, A in 128 regs), wc=w&3 code quarter.
// Window = 32 codes x 64 k = 4 KB, 256 windows. Wave-private 4-deep LDS
// buffers + register-pipelined fragments:
//   iter n: lgkm(0) [prior ds_reads retired -> buf[n&3] recyclable]
//           STAGE(n+4 -> buf[n&3])
//           vmcnt(8) [drains st(n+1); robust even if a staging group sinks]
//           ds_read frags(n+1) -> regB[(n+1)&1]
//           16 MFMAs on regB[n&1]   (all latencies pre-hidden)
// Dummy wrap-around staging keeps the vmcnt accounting uniform at the tail.
__global__ __launch_bounds__(512, 2) void vq_main(const unsigned short* __restrict__ cbb,
                                                  const float* __restrict__ w2g,
                                                  const float* __restrict__ z_e,
                                                  const float* __restrict__ cb,
                                                  float* __restrict__ out,
                                                  int* __restrict__ flags) {
    __shared__ unsigned short ca[8][4][2048];   // [wave][buf][4 KB] = 128 KB
    __shared__ unsigned long long smin[128];
    __shared__ float wls[8];

    const int tid  = threadIdx.x;
    const int lane = tid & 63;
    const int w    = tid >> 6;        // 0..7
    const int wr   = w >> 2;          // token half
    const int wc   = w & 3;           // code quarter
    const int quad = lane >> 4;
    const int l15  = lane & 15;
    const int t0   = blockIdx.x * 128;

    if (tid < 128) smin[tid] = ~0ULL;
    __syncthreads();                  // smin published before any wave's epilogue

    // staging: window WIN (0..255): chunk _c=WIN>>2 (codes _c*128+wc*32+lr),
    // k-window _kw=WIN&3 (k in [_kw*64, _kw*64+64)). 4 loads x 1 KB, each
    // covering 8 rows x 128 B. Source k-slot XOR-swizzled by row for
    // conflict-free ds_read_b128 later.
    const int srow = lane >> 3;       // 0..7
    const int ssl  = lane & 7;        // LDS slot position
    #define STAGE(WIN, BP)                                                              \
        {                                                                               \
            int _c  = (WIN) >> 2;                                                       \
            int _kw = (WIN) & 3;                                                        \
            _Pragma("unroll")                                                           \
            for (int q = 0; q < 4; ++q) {                                               \
                int lr = q * 8 + srow;                                                  \
                int sl = ssl ^ (lr & 7);                                                \
                __builtin_amdgcn_global_load_lds(                                       \
                    (const __attribute__((address_space(1))) void*)                     \
                        (cbb + (size_t)(_c * 128 + wc * 32 + lr) * DIM + _kw * 64 + sl * 8), \
                    (__attribute__((address_space(3))) void*)(&ca[w][BP][q * 512]),     \
                    16, 0, 0);                                                          \
            }                                                                           \
        }

    // read the 4 fragments of window WIN from buf BP into FB[kk*2+j]
    #define READFRAGS(FB, WIN, BP)                                                      \
        {                                                                               \
            _Pragma("unroll")                                                           \
            for (int kk = 0; kk < 2; ++kk)                                              \
                _Pragma("unroll")                                                       \
                for (int j = 0; j < 2; ++j) {                                           \
                    int row = j * 16 + l15;                                             \
                    int sl = (kk * 4 + quad) ^ (l15 & 7);                               \
                    (FB)[kk * 2 + j] = *(const s16x8*)(&ca[w][BP][row * 64 + sl * 8]);  \
                }                                                                       \
        }

    // prologue: stage windows 0..3, then build A from fp32 z_e
    STAGE(0, 0); STAGE(1, 1); STAGE(2, 2); STAGE(3, 3);
    s16x8 af[4][8];
    #pragma unroll
    for (int i = 0; i < 4; ++i) {
        #pragma unroll
        for (int ks = 0; ks < 8; ++ks) {
            const float* p = z_e + (size_t)(t0 + wr * 64 + i * 16 + l15) * DIM + ks * 32 + quad * 8;
            float4 a = *(const float4*)p;
            float4 b = *(const float4*)(p + 4);
            s16x8 v;
            v[0] = (short)f2bf(a.x); v[1] = (short)f2bf(a.y);
            v[2] = (short)f2bf(a.z); v[3] = (short)f2bf(a.w);
            v[4] = (short)f2bf(b.x); v[5] = (short)f2bf(b.y);
            v[6] = (short)f2bf(b.z); v[7] = (short)f2bf(b.w);
            af[i][ks] = v;
        }
    }

    float best[4][4];
    int   bidx[4][4];
    #pragma unroll
    for (int i = 0; i < 4; ++i)
        #pragma unroll
        for (int r = 0; r < 4; ++r) { best[i][r] = FLT_MAX; bidx[i][r] = 0x7FFFFFFF; }

    // prime: window 0 frags into regB[0] (vmcnt(12): st0..3 + A outstanding,
    // leaves newest 12 -> st0 certainly drained)
    s16x8 regB[2][4];
    __builtin_amdgcn_s_waitcnt(0x0F7C);   // vmcnt(12), lgkm/exp unconstrained
    READFRAGS(regB[0], 0, 0);

    for (int c = 0; c < 64; ++c) {
        f32x4 acc[4][2];
        #pragma unroll
        for (int i = 0; i < 4; ++i)
            #pragma unroll
            for (int j = 0; j < 2; ++j) acc[i][j] = (f32x4){0.f, 0.f, 0.f, 0.f};

        #pragma unroll
        for (int kw = 0; kw < 4; ++kw) {
            const int n = c * 4 + kw;
            // prior ds_reads retired -> buf[n&3] is recyclable for staging
            __builtin_amdgcn_s_waitcnt(0xC07F);   // lgkmcnt(0), vmcnt/exp unconstrained
            STAGE((n + 4) & 255, n & 3);          // wrap keeps accounting uniform
            // drain staging of window n+1 (robust: st(n+2)+st(n+3)=8 newer)
            __builtin_amdgcn_s_waitcnt(0x0F78);   // vmcnt(8), lgkm/exp unconstrained
            READFRAGS(regB[(n + 1) & 1], (n + 1) & 255, (n + 1) & 3);
            // 16 MFMAs on window n (fragments read one iteration ago)
            const s16x8* cur = regB[n & 1];
            #pragma unroll
            for (int kk = 0; kk < 2; ++kk)
                #pragma unroll
                for (int i = 0; i < 4; ++i)
                    #pragma unroll
                    for (int j = 0; j < 2; ++j)
                        acc[i][j] = __builtin_amdgcn_mfma_f32_16x16x32_bf16(af[i][kw * 2 + kk], cur[kk * 2 + j], acc[i][j], 0, 0, 0);
        }

        // fold chunk c into running argmin: score = w2[col] - 2*dot
        #pragma unroll
        for (int j = 0; j < 2; ++j) {
            int col = c * 128 + wc * 32 + j * 16 + l15;
            float w2v = w2g[col];
            #pragma unroll
            for (int i = 0; i < 4; ++i)
                #pragma unroll
                for (int r = 0; r < 4; ++r) {
                    float s = fmaf(-2.0f, acc[i][j][r], w2v);
                    if (s < best[i][r]) { best[i][r] = s; bidx[i][r] = col; }  // ascending col: < keeps lowest
                }
        }
    }

    // cross-lane argmin over the 16 cols held per token row, then merge quarters
    #pragma unroll
    for (int i = 0; i < 4; ++i)
        #pragma unroll
        for (int r = 0; r < 4; ++r) {
            float b = best[i][r]; int ix = bidx[i][r];
            #pragma unroll
            for (int m = 1; m < 16; m <<= 1) {
                float ob = __shfl_xor(b, m);
                int   oi = __shfl_xor(ix, m);
                if (ob < b || (ob == b && oi < ix)) { b = ob; ix = oi; }
            }
            if (l15 == 0) {
                unsigned int fb = __float_as_uint(b);
                fb = (fb & 0x80000000u) ? ~fb : (fb | 0x80000000u);   // monotonic key
                unsigned long long key = ((unsigned long long)fb << 32) | (unsigned int)ix;
                atomicMin(&smin[wr * 64 + i * 16 + quad * 4 + r], key);
            }
        }
    __syncthreads();   // all waves' argmin merged before gather

    // fused gather + loss + flags: wave w -> tokens [w*16, w*16+16)
    float lsum = 0.0f;
    for (int t = w * 16; t < w * 16 + 16; ++t) {
        int tok = t0 + t;
        int k = (int)(unsigned int)(smin[t] & 0xFFFFFFFFull);
        if (lane == 0) flags[k] = 1;   // benign race
        float4 cv = *(const float4*)(cb + (size_t)k * DIM + lane * 4);
        float4 zv = *(const float4*)(z_e + (size_t)tok * DIM + lane * 4);
        float dx = zv.x - cv.x, dy = zv.y - cv.y, dz = zv.z - cv.z, dw = zv.w - cv.w;
        lsum += dx * dx + dy * dy + dz * dz + dw * dw;
        *(float4*)(out + (size_t)tok * DIM + lane * 4) = cv;
    }
    #pragma unroll
    for (int m = 32; m >= 1; m >>= 1) lsum += __shfl_xor(lsum, m);
    if (lane == 0) wls[w] = lsum;
    __syncthreads();
    if (tid == 0) {
        float bsum = 0.0f;
        #pragma unroll
        for (int q = 0; q < 8; ++q) bsum += wls[q];
        // loss = codebook + 0.25*commitment = 1.25 * mean(diff^2)
        atomicAdd(out + LOSS_IDX, bsum * (1.25f / (float)LOSS_IDX));
    }
}

// ---------------------------------------------------------------------------
__global__ __launch_bounds__(256) void vq_usage(const int* __restrict__ flags,
                                                float* __restrict__ out) {
    __shared__ int ws[4];
    int tid = threadIdx.x;
    int s = 0;
    for (int i = tid; i < KC; i += 256) s += flags[i];
    #pragma unroll
    for (int m = 32; m >= 1; m >>= 1) s += __shfl_xor(s, m);
    if ((tid & 63) == 0) ws[tid >> 6] = s;
    __syncthreads();
    if (tid == 0) out[USAGE_IDX] = (float)(ws[0] + ws[1] + ws[2] + ws[3]) / (float)KC;
}

// ---------------------------------------------------------------------------
extern "C" void kernel_launch(void* const* d_in, const int* in_sizes, int n_in,
                              void* d_out, int out_size, void* d_ws, size_t ws_size,
                              hipStream_t stream) {
    (void)in_sizes; (void)n_in; (void)out_size; (void)ws_size;
    const float* z_e = (const float*)d_in[0];
    const float* cb  = (const float*)d_in[1];
    float* out = (float*)d_out;

    char* ws = (char*)d_ws;
    float* w2    = (float*)(ws + WS_W2);
    int*   flags = (int*)(ws + WS_FLAGS);
    unsigned short* cbb = (unsigned short*)(ws + WS_CBF);

    vq_prep<<<KC / 8, 256, 0, stream>>>(cb, cbb, w2, flags, out);
    vq_main<<<T_TOTAL / 128, 512, 0, stream>>>(cbb, w2, z_e, cb, out, flags);
    vq_usage<<<1, 256, 0, stream>>>(flags, out);
}